// Round 1
// baseline (667.840 us; speedup 1.0000x reference)
//
#include <hip/hip_runtime.h>

// Problem constants: src [B,C,D,H,W] fp32, v [B,2,D,H,W] fp32, out [B,C,D,H,W] fp32
#define NB 8
#define NC 4
#define ND 32
#define NH 256
#define NW 256

// HW = 65536, DHW = 2097152
__global__ __launch_bounds__(256) void st_warp_kernel(const float* __restrict__ src,
                                                      const float* __restrict__ v,
                                                      float* __restrict__ out) {
    const int HW  = NH * NW;
    const int DHW = ND * HW;

    int idx = blockIdx.x * 256 + threadIdx.x;   // 0 .. B*D*H*W-1 (16M, fits int)
    int x  = idx & (NW - 1);
    int y  = (idx >> 8) & (NH - 1);
    int bd = idx >> 16;          // b*ND + d
    int b  = bd >> 5;            // ND = 32

    // v[b,ch,d,h,w] = v[b*2*DHW + ch*DHW + s], s = idx - b*DHW
    int s   = idx - b * DHW;     // d*HW + y*W + x
    int vof = b * 2 * DHW + s;
    float vx = v[vof];
    float vy = v[vof + DHW];

    // normalize/unnormalize: ix = (x+vx) * (W-1)/(H-1), iy = y + vy
    const float sx = (float)(NW - 1) / (float)(NH - 1);
    float fx = ((float)x + vx) * sx;
    float fy = (float)y + vy;

    float x0f = floorf(fx);
    float y0f = floorf(fy);
    float wx1 = fx - x0f, wx0 = 1.0f - wx1;
    float wy1 = fy - y0f, wy0 = 1.0f - wy1;

    int x0 = (int)x0f;
    int y0 = (int)y0f;
    int x1 = x0 + 1;
    int y1 = y0 + 1;

    bool vx0 = (x0 >= 0) & (x0 <= NW - 1);
    bool vx1 = (x1 >= 0) & (x1 <= NW - 1);
    bool vy0 = (y0 >= 0) & (y0 <= NH - 1);
    bool vy1 = (y1 >= 0) & (y1 <= NH - 1);

    int x0c = min(max(x0, 0), NW - 1);
    int x1c = min(max(x1, 0), NW - 1);
    int y0c = min(max(y0, 0), NH - 1);
    int y1c = min(max(y1, 0), NH - 1);

    float w00 = (vx0 && vy0) ? wx0 * wy0 : 0.0f;
    float w10 = (vx1 && vy0) ? wx1 * wy0 : 0.0f;
    float w01 = (vx0 && vy1) ? wx0 * wy1 : 0.0f;
    float w11 = (vx1 && vy1) ? wx1 * wy1 : 0.0f;

    // src[b,c,d,.,.] base = b*NC*DHW + c*DHW + d*HW; (d*HW) = s - y*W - x
    int dHW   = s - (y << 8) - x;          // d*HW
    int sbase = b * NC * DHW + dHW;
    int r0 = (y0c << 8);
    int r1 = (y1c << 8);

    // out[b,c,d,h,w] = out[b*NC*DHW + c*DHW + s]
    int obase = b * NC * DHW + s;

#pragma unroll
    for (int c = 0; c < NC; ++c) {
        const float* p = src + sbase + c * DHW;
        float s00 = p[r0 + x0c];
        float s10 = p[r0 + x1c];
        float s01 = p[r1 + x0c];
        float s11 = p[r1 + x1c];
        out[obase + c * DHW] = s00 * w00 + s10 * w10 + s01 * w01 + s11 * w11;
    }
}

extern "C" void kernel_launch(void* const* d_in, const int* in_sizes, int n_in,
                              void* d_out, int out_size, void* d_ws, size_t ws_size,
                              hipStream_t stream) {
    const float* src = (const float*)d_in[0];
    const float* v   = (const float*)d_in[1];
    float* out       = (float*)d_out;

    int n = NB * ND * NH * NW;          // 16,777,216 threads
    dim3 grid(n / 256), block(256);
    st_warp_kernel<<<grid, block, 0, stream>>>(src, v, out);
}